// Round 2
// baseline (28.535 us; speedup 1.0000x reference)
//
#include <hip/hip_runtime.h>
#include <math.h>

// Problem constants
#define N_CL 128      // N clusters
#define M_SPK 16      // M rows per cluster
#define P_DIM 256     // feature dim
#define NM 2048       // N*M rows
#define NBLK 256      // k2 blocks (8 rows each)
static constexpr float EPS_NORM = 1e-12f;
static constexpr float EPS_LOG  = 1e-9f;

// ws layout (float offsets):
//   centT     [P_DIM][N_CL] @ 0       (32768 floats), cent_sum transposed (p-major)
//   blockloss [NBLK]        @ 32768
//   cnt       (1 uint)      @ 33024
#define WS_CENTT     0
#define WS_BLOCKLOSS 32768
#define WS_CNT       33024

__device__ __forceinline__ float waveReduceSum(float x) {
    #pragma unroll
    for (int off = 32; off > 0; off >>= 1)
        x += __shfl_xor(x, off, 64);
    return x;
}

// Kernel 1: per-cluster centroid sums, stored transposed centT[p][n].
// grid = 128 (block per cluster), block = 256 (thread per p). Also zeroes cnt.
__global__ __launch_bounds__(256)
void k1_cent(const float* __restrict__ e, float* __restrict__ ws,
             unsigned* __restrict__ cnt) {
    const int n = blockIdx.x;
    const int p = threadIdx.x;
    const float* base = e + (size_t)n * (M_SPK * P_DIM) + p;
    float acc = 0.f;
    #pragma unroll
    for (int m = 0; m < M_SPK; ++m) acc += base[m * P_DIM];
    ws[WS_CENTT + p * N_CL + n] = acc;   // scattered store, 128 KB total (L2 absorbs)
    if (n == 0 && p == 0) *cnt = 0u;
}

// Kernel 2 (fused): s matrix + row logsumexp + final loss (last block reduces).
// grid = 256, block = 256 (4 waves). Block handles rows [8b, 8b+8), all 128 n'.
// Wave w: row-group g=w&1 -> rows 8b+4g..+3 ; n-half h=w>>1 -> n' = 64h+lane.
__global__ __launch_bounds__(256)
void k2_fused(const float* __restrict__ e, const float* __restrict__ ws_ro,
              float* __restrict__ d_out, float* __restrict__ blockloss,
              unsigned* __restrict__ cnt) {
    const int bid  = blockIdx.x;
    const int t    = threadIdx.x;
    const int lane = t & 63;
    const int w    = t >> 6;
    const int g    = w & 1;
    const int h    = w >> 1;
    const int k0   = bid * 8;
    const int nk   = k0 >> 4;          // cluster id (uniform; 8-row block within one cluster)
    const int np   = h * 64 + lane;    // this lane's n'

    const float* centT = ws_ro + WS_CENTT;

    __shared__ float eL[8][P_DIM];
    __shared__ float partial[8][2];
    __shared__ float own_s[8];
    __shared__ float vv[8];
    __shared__ float wp[4];
    __shared__ int   lastFlag;

    // stage the block's 8 e-rows (perfectly coalesced, stride-1 LDS writes)
    #pragma unroll
    for (int i = 0; i < 8; ++i)
        ((float*)eL)[i * 256 + t] = e[(size_t)k0 * P_DIM + i * 256 + t];
    if (t == 0) lastFlag = 0;
    __syncthreads();

    // per-row ||e||^2 for this wave's 4 rows (conflict-free stride-1 LDS reads)
    float e2[4], rek[4];
    #pragma unroll
    for (int r = 0; r < 4; ++r) {
        const float* row = eL[4 * g + r];
        float x0 = row[lane], x1 = row[lane + 64], x2 = row[lane + 128], x3 = row[lane + 192];
        float s2 = waveReduceSum(x0 * x0 + x1 * x1 + x2 * x2 + x3 * x3);
        e2[r]  = s2;
        rek[r] = 1.0f / sqrtf(s2 + EPS_NORM);
    }

    // main loop: 4 rows x 1 n' per lane; cent column streamed once per wave,
    // cluster norm csn[np] accumulated on the fly (cacc).
    float dot[4] = {0.f, 0.f, 0.f, 0.f};
    float cacc = 0.f;
    const float* cptr = centT + np;
    #pragma unroll 2
    for (int p = 0; p < P_DIM; p += 4) {
        float c0 = cptr[(p + 0) * N_CL];
        float c1 = cptr[(p + 1) * N_CL];
        float c2 = cptr[(p + 2) * N_CL];
        float c3 = cptr[(p + 3) * N_CL];
        cacc = fmaf(c0, c0, cacc);
        cacc = fmaf(c1, c1, cacc);
        cacc = fmaf(c2, c2, cacc);
        cacc = fmaf(c3, c3, cacc);
        #pragma unroll
        for (int r = 0; r < 4; ++r) {
            float4 ev = *(const float4*)&eL[4 * g + r][p];   // uniform addr -> broadcast
            dot[r] = fmaf(ev.x, c0, dot[r]);
            dot[r] = fmaf(ev.y, c1, dot[r]);
            dot[r] = fmaf(ev.z, c2, dot[r]);
            dot[r] = fmaf(ev.w, c3, dot[r]);
        }
    }

    // epilogue: s values + per-row exp sums
    const float sc_oth = 1.0f / sqrtf(cacc + (float)(M_SPK * M_SPK) * EPS_NORM);
    float svals[4];
    #pragma unroll
    for (int r = 0; r < 4; ++r) {
        float s;
        if (np == nk) {
            // own column: h_cent = (cent_sum - e)/15
            float num = (dot[r] - e2[r]) * (1.0f / 15.0f);
            float hh  = (cacc - 2.0f * dot[r] + e2[r]) * (1.0f / 225.0f);
            s = 10.0f * (num * rek[r] / sqrtf(hh + EPS_NORM)) - 5.0f;
        } else {
            s = 10.0f * (dot[r] * rek[r] * sc_oth) - 5.0f;
        }
        svals[r] = s;
        const int k = k0 + 4 * g + r;
        d_out[1 + (size_t)k * N_CL + np] = s;   // coalesced 256B per row per wave
    }
    #pragma unroll
    for (int r = 0; r < 4; ++r) {
        float exsum = waveReduceSum(expf(svals[r]));
        if (lane == 0) partial[4 * g + r][h] = exsum;
    }
    if (np == nk) {
        #pragma unroll
        for (int r = 0; r < 4; ++r) own_s[4 * g + r] = svals[r];
    }
    __syncthreads();

    if (t < 8) {
        float tot = partial[t][0] + partial[t][1];
        vv[t] = logf(tot + EPS_LOG) - own_s[t];
    }
    __syncthreads();

    if (t == 0) {
        float bl = 0.f;
        #pragma unroll
        for (int i = 0; i < 8; ++i) bl += vv[i];
        __hip_atomic_store(&blockloss[bid], bl, __ATOMIC_RELAXED, __HIP_MEMORY_SCOPE_AGENT);
        unsigned old = __hip_atomic_fetch_add(cnt, 1u, __ATOMIC_ACQ_REL, __HIP_MEMORY_SCOPE_AGENT);
        lastFlag = (old == NBLK - 1) ? 1 : 0;
    }
    __syncthreads();

    // deterministic final reduction in the last-arriving block (fixed tree order)
    if (lastFlag) {
        float v = __hip_atomic_load(&blockloss[t], __ATOMIC_RELAXED, __HIP_MEMORY_SCOPE_AGENT);
        float sum = waveReduceSum(v);
        if (lane == 0) wp[w] = sum;
        __syncthreads();
        if (t == 0) d_out[0] = (wp[0] + wp[1] + wp[2] + wp[3]) * (1.0f / NM);
    }
}

extern "C" void kernel_launch(void* const* d_in, const int* in_sizes, int n_in,
                              void* d_out, int out_size, void* d_ws, size_t ws_size,
                              hipStream_t stream) {
    const float* e = (const float*)d_in[0];
    float* out = (float*)d_out;
    float* ws  = (float*)d_ws;
    unsigned* cnt = (unsigned*)(ws + WS_CNT);

    k1_cent<<<N_CL, 256, 0, stream>>>(e, ws, cnt);
    k2_fused<<<NBLK, 256, 0, stream>>>(e, ws, out, ws + WS_BLOCKLOSS, cnt);
}

// Round 3
// 22.596 us; speedup vs baseline: 1.2629x; 1.2629x over previous
//
#include <hip/hip_runtime.h>
#include <math.h>

// Problem constants
#define N_CL 128      // N clusters
#define M_SPK 16      // M rows per cluster
#define P_DIM 256     // feature dim
#define NM 2048       // N*M rows
#define K2_BLOCKS 512 // k2: 4 rows per block
static constexpr float EPS_NORM = 1e-12f;
static constexpr float EPS_LOG  = 1e-9f;

// ws layout (float offsets):
//   centT     [P_DIM][N_CL] @ 0      (32768 floats) cent_sum transposed (p-major)
//   blockloss [K2_BLOCKS]   @ 32768
//   cnt       (1 uint)      @ 33280
#define WS_CENTT     0
#define WS_BLOCKLOSS 32768
#define WS_CNT       33280

__device__ __forceinline__ float waveReduceSum(float x) {
    #pragma unroll
    for (int off = 32; off > 0; off >>= 1)
        x += __shfl_xor(x, off, 64);
    return x;
}

// k1: per-cluster centroid sums, transposed store centT[p][n]. Also zeroes cnt.
// grid = 256 (cluster n = bid>>1, p-half = bid&1), block = 128.
__global__ __launch_bounds__(128)
void k1_cent(const float* __restrict__ e, float* __restrict__ ws,
             unsigned* __restrict__ cnt) {
    const int bid = blockIdx.x;
    const int n   = bid >> 1;
    const int p   = ((bid & 1) << 7) + threadIdx.x;
    const float* base = e + (size_t)n * (M_SPK * P_DIM) + p;
    float acc = 0.f;
    #pragma unroll
    for (int m = 0; m < M_SPK; ++m) acc += base[m * P_DIM];
    ws[WS_CENTT + p * N_CL + n] = acc;   // 128 KB scatter total; L2 absorbs
    if (bid == 0 && threadIdx.x == 0) *cnt = 0u;
}

// k2 (fused): s matrix + row logsumexp + final loss via relaxed-atomic last-block tail.
// grid = 512 (rows [4b,4b+4)), block = 512 = 8 waves.
// Wave w = p-split ps: p in [32w, 32w+32); lane covers cols {2*lane, 2*lane+1}, all 4 rows.
__global__ __launch_bounds__(512, 4)
void k2_fused(const float* __restrict__ e, const float* __restrict__ ws_ro,
              float* __restrict__ d_out, float* __restrict__ blockloss,
              unsigned* __restrict__ cnt) {
    const int bid  = blockIdx.x;
    const int t    = threadIdx.x;
    const int lane = t & 63;
    const int w    = t >> 6;        // ps = 0..7
    const int k0   = bid * 4;
    const int nk   = bid >> 2;      // cluster of these 4 rows (16 rows/cluster)

    const float* centT = ws_ro + WS_CENTT;

    __shared__ float eL[4][P_DIM];
    __shared__ float pd[8][4][N_CL];    // partial dots [ps][r][col]
    __shared__ float caccp[8][N_CL];    // partial ||cent||^2 [ps][col]
    __shared__ float e2L[4], rekL[4], ownSL[4], vvL[4];
    __shared__ float expPart[8];
    __shared__ float wp[8];
    __shared__ int   lastFlag;

    // stage 4 e-rows (1024 floats, coalesced)
    {
        const float* src = e + (size_t)k0 * P_DIM;
        ((float*)eL)[t]       = src[t];
        ((float*)eL)[t + 512] = src[t + 512];
    }
    if (t == 0) lastFlag = 0;
    __syncthreads();

    // row norms: wave r (r<4) reduces row r
    if (w < 4) {
        const float* row = eL[w];
        float x0 = row[lane], x1 = row[lane + 64], x2 = row[lane + 128], x3 = row[lane + 192];
        float s2 = waveReduceSum(x0 * x0 + x1 * x1 + x2 * x2 + x3 * x3);
        if (lane == 0) { e2L[w] = s2; rekL[w] = 1.0f / sqrtf(s2 + EPS_NORM); }
    }

    // main loop: 32 p-steps, float2 (2 cols) per lane, 4 rows
    float2 dot2[4] = {{0.f,0.f},{0.f,0.f},{0.f,0.f},{0.f,0.f}};
    float2 cac2 = {0.f, 0.f};
    const float2* cbase = (const float2*)centT + lane;   // + p*64 (row stride in float2)
    const int pbase = w * 32;
    #pragma unroll 2
    for (int p0 = 0; p0 < 32; p0 += 4) {
        float2 c0 = cbase[(pbase + p0 + 0) * 64];
        float2 c1 = cbase[(pbase + p0 + 1) * 64];
        float2 c2 = cbase[(pbase + p0 + 2) * 64];
        float2 c3 = cbase[(pbase + p0 + 3) * 64];
        cac2.x = fmaf(c0.x, c0.x, cac2.x); cac2.y = fmaf(c0.y, c0.y, cac2.y);
        cac2.x = fmaf(c1.x, c1.x, cac2.x); cac2.y = fmaf(c1.y, c1.y, cac2.y);
        cac2.x = fmaf(c2.x, c2.x, cac2.x); cac2.y = fmaf(c2.y, c2.y, cac2.y);
        cac2.x = fmaf(c3.x, c3.x, cac2.x); cac2.y = fmaf(c3.y, c3.y, cac2.y);
        #pragma unroll
        for (int r = 0; r < 4; ++r) {
            float4 ev = *(const float4*)&eL[r][pbase + p0];   // broadcast LDS b128
            dot2[r].x = fmaf(ev.x, c0.x, dot2[r].x); dot2[r].y = fmaf(ev.x, c0.y, dot2[r].y);
            dot2[r].x = fmaf(ev.y, c1.x, dot2[r].x); dot2[r].y = fmaf(ev.y, c1.y, dot2[r].y);
            dot2[r].x = fmaf(ev.z, c2.x, dot2[r].x); dot2[r].y = fmaf(ev.z, c2.y, dot2[r].y);
            dot2[r].x = fmaf(ev.w, c3.x, dot2[r].x); dot2[r].y = fmaf(ev.w, c3.y, dot2[r].y);
        }
    }
    // store partials (b64, 2-way bank alias = free)
    {
        const int col0 = lane << 1;
        #pragma unroll
        for (int r = 0; r < 4; ++r)
            *(float2*)&pd[w][r][col0] = dot2[r];
        *(float2*)&caccp[w][col0] = cac2;
    }
    __syncthreads();

    // epilogue: thread t -> (r = t>>7, col = t&127)
    const int r   = t >> 7;
    const int col = t & 127;
    float dotv = 0.f, cv = 0.f;
    #pragma unroll
    for (int ps = 0; ps < 8; ++ps) { dotv += pd[ps][r][col]; cv += caccp[ps][col]; }

    const float rek = rekL[r];
    float s;
    if (col == nk) {
        const float e2 = e2L[r];
        const float num = (dotv - e2) * (1.0f / 15.0f);
        const float hh  = (cv - 2.0f * dotv + e2) * (1.0f / 225.0f);
        s = 10.0f * (num * rek / sqrtf(hh + EPS_NORM)) - 5.0f;
        ownSL[r] = s;
    } else {
        s = 10.0f * (dotv * rek * (1.0f / sqrtf(cv + (float)(M_SPK * M_SPK) * EPS_NORM))) - 5.0f;
    }
    d_out[1 + (size_t)(k0 + r) * N_CL + col] = s;

    // per-row logsumexp: row r = waves {2r, 2r+1}
    float psum = waveReduceSum(__expf(s));
    if (lane == 0) expPart[w] = psum;
    __syncthreads();
    if (t < 4)
        vvL[t] = __logf(expPart[2 * t] + expPart[2 * t + 1] + EPS_LOG) - ownSL[t];
    __syncthreads();

    // tail: relaxed agent atomics only (coherent at MALL); no per-block fences
    if (t == 0) {
        float bl = vvL[0] + vvL[1] + vvL[2] + vvL[3];
        __hip_atomic_store(&blockloss[bid], bl, __ATOMIC_RELAXED, __HIP_MEMORY_SCOPE_AGENT);
        asm volatile("s_waitcnt vmcnt(0)" ::: "memory");   // blockloss visible before cnt++
        unsigned old = __hip_atomic_fetch_add(cnt, 1u, __ATOMIC_RELAXED, __HIP_MEMORY_SCOPE_AGENT);
        lastFlag = (old == K2_BLOCKS - 1) ? 1 : 0;
    }
    __syncthreads();

    // winner block: deterministic fixed-tree reduction of 512 block losses
    if (lastFlag) {
        __builtin_amdgcn_fence(__ATOMIC_ACQUIRE, "agent");  // once, winner only
        float v = __hip_atomic_load(&blockloss[t], __ATOMIC_RELAXED, __HIP_MEMORY_SCOPE_AGENT);
        float sum = waveReduceSum(v);
        if (lane == 0) wp[w] = sum;
        __syncthreads();
        if (t == 0) {
            float tot = 0.f;
            #pragma unroll
            for (int i = 0; i < 8; ++i) tot += wp[i];
            d_out[0] = tot * (1.0f / NM);
        }
    }
}

extern "C" void kernel_launch(void* const* d_in, const int* in_sizes, int n_in,
                              void* d_out, int out_size, void* d_ws, size_t ws_size,
                              hipStream_t stream) {
    const float* e = (const float*)d_in[0];
    float* out = (float*)d_out;
    float* ws  = (float*)d_ws;
    unsigned* cnt = (unsigned*)(ws + WS_CNT);

    k1_cent<<<256, 128, 0, stream>>>(e, ws, cnt);
    k2_fused<<<K2_BLOCKS, 512, 0, stream>>>(e, ws, out, ws + WS_BLOCKLOSS, cnt);
}